// Round 7
// baseline (2838.070 us; speedup 1.0000x reference)
//
#include <hip/hip_runtime.h>
#include <hip/hip_bf16.h>

// RecallModel: B=16, L=2048, H=64, NH=2, HD=32, M=8, V=64.
// Inputs: ints int32; floats FP32. OUTPUTS FLOAT32 (reference dtype!):
//   out_f[0] = loss, out_f[1..1+16*2048*2048) = attn_w (B,L,L). 268,435,460 B.
//
// d_ws usage: 918,020 bytes (proven functional rounds 4-6):
//   qk15 @0       524,288 B  bf16 [Qs|K] batch 15 (layer 2)
//   imp  @524288  131,072 B  f32 imp[16][2048]
//   l2   @655360  262,144 B  f32 sum-of-exp
//   topk @917504      512 B
//   loss @918016        4 B  f32
// d_out doubles as scratch (dead-before-overwrite). attn batch-b region =
// bytes [4 + b*16777216, 4 + (b+1)*16777216).
//   h      @ byte 64         4 MB bf16 (region 0; dies at k_loss, before pass2)
//   qkv/v  @ byte 4194368   12 MB bf16 (layer-1 [Qs|K|V] s192 -> layer-2 V s64;
//                                  dies at attn; tiny spill into region 1 is dead too)
//   qk0-14 @ byte 251658304 7.7 MB (region 15; dies at pass2 wave1)
// pass2 wave1 (bz 0..14) writes regions 0..14 (reads park in region 15);
// wave2 (bz 15) reads d_ws, overwrites region 15. Loss stored LAST to out_f[0].

typedef unsigned short u16;
#define LQ 2048
#define BBATCH 16
#define QKB 262144   // u16 elements per batch of packed [Qs|K] (2048*128)

__device__ __forceinline__ float bfu2f(u16 x){ return __uint_as_float(((unsigned)x) << 16); }
__device__ __forceinline__ u16 f2bu(float f){ return __bfloat16_as_ushort(__float2bfloat16(f)); }

__device__ __forceinline__ const u16* qk_rowp(const u16* qk_r15, const u16* qk_ws,
                                              int bz, int row){
  const u16* base = (bz < 15) ? (qk_r15 + (size_t)bz*QKB) : qk_ws;
  return base + (size_t)row*128;
}
__device__ __forceinline__ u16* qk_rowp_w(u16* qk_r15, u16* qk_ws, int bz, int row){
  u16* base = (bz < 15) ? (qk_r15 + (size_t)bz*QKB) : qk_ws;
  return base + (size_t)row*128;
}

// load 8 consecutive bf16 (16 B) -> 8 fp32 (internal buffers only)
__device__ __forceinline__ void ld8bf(const u16* p, float o[8]){
  uint4 r = *(const uint4*)p;
  unsigned v[4] = {r.x, r.y, r.z, r.w};
  #pragma unroll
  for (int i=0;i<4;i++){
    o[2*i]   = __uint_as_float((v[i] & 0xffffu) << 16);
    o[2*i+1] = __uint_as_float(v[i] & 0xffff0000u);
  }
}

// ---------------- embed ----------------
__global__ __launch_bounds__(256) void k_embed(const int* __restrict__ seq,
                                               const float* __restrict__ emb,
                                               u16* __restrict__ h){
  int i = blockIdx.x*256 + threadIdx.x;      // 32768*64
  int tok = i >> 6, d = i & 63;
  int v = seq[tok] & 63;
  h[i] = f2bu(emb[(v << 6) + d]);
}

__global__ __launch_bounds__(256) void k_zero(float* __restrict__ p){
  p[blockIdx.x*256 + threadIdx.x] = 0.f;
}

// ---------------- qkv projection ----------------
template<int MODE>
__global__ __launch_bounds__(256) void k_qkv(const u16* __restrict__ X,
                                             const float* __restrict__ W,
                                             const float* __restrict__ bias,
                                             u16* __restrict__ dqkv,
                                             u16* __restrict__ dqk_r15,
                                             u16* __restrict__ dqk_ws,
                                             u16* __restrict__ dv){
  __shared__ float WT[64*193];   // [k][mo]
  __shared__ float bs[192];
  const int t = threadIdx.x;
  for (int e=t; e<192*64; e+=256){ int mo=e>>6, k=e&63; WT[k*193+mo] = W[e]; }
  if (t < 192) bs[t] = bias[t];
  __syncthreads();
  const int wid=t>>6, lane=t&63;
  const int tok0 = (blockIdx.x*4 + wid)*4;
  float x[4];
  #pragma unroll
  for (int c=0;c<4;c++) x[c] = bfu2f(X[(tok0+c)*64 + lane]);
  float acc[4][3];
  #pragma unroll
  for (int c=0;c<4;c++)
    #pragma unroll
    for (int m=0;m<3;m++) acc[c][m] = bs[m*64 + lane];
  for (int k=0;k<64;k++){
    float wv[3];
    #pragma unroll
    for (int m=0;m<3;m++) wv[m] = WT[k*193 + m*64 + lane];
    #pragma unroll
    for (int c=0;c<4;c++){
      float xk = __shfl(x[c], k);
      #pragma unroll
      for (int m=0;m<3;m++) acc[c][m] += xk*wv[m];
    }
  }
  const float qs = 0.17677669529663688f;  // 1/sqrt(32)
  #pragma unroll
  for (int c=0;c<4;c++){
    int tok = tok0+c;
    float vq = acc[c][0]*qs, vk = acc[c][1], vv = acc[c][2];
    if (MODE==0){
      dqkv[tok*192 + lane]       = f2bu(vq);
      dqkv[tok*192 + 64 + lane]  = f2bu(vk);
      dqkv[tok*192 + 128 + lane] = f2bu(vv);
    } else {
      int b = tok >> 11, r = tok & 2047;
      u16* row = qk_rowp_w(dqk_r15, dqk_ws, b, r);
      row[lane]      = f2bu(vq);
      row[64 + lane] = f2bu(vk);
      dv[tok*64 + lane] = f2bu(vv);
    }
  }
}

// ---------------- score/exp + PV helpers ----------------
__device__ __forceinline__ void score_exp_tile(const float* Qb, const float* Kb,
                                               int qi4, int ji4, float e[4][4]){
  float a[4][4];
  #pragma unroll
  for (int qq=0;qq<4;qq++)
    #pragma unroll
    for (int jj=0;jj<4;jj++) a[qq][jj] = 0.f;
  for (int d=0; d<32; d++){
    float4 qv4 = *(const float4*)(Qb + d*64 + qi4*4);
    float4 kv4 = *(const float4*)(Kb + d*64 + ji4*4);
    float qv[4] = {qv4.x,qv4.y,qv4.z,qv4.w};
    float kv[4] = {kv4.x,kv4.y,kv4.z,kv4.w};
    #pragma unroll
    for (int qq=0;qq<4;qq++)
      #pragma unroll
      for (int jj=0;jj<4;jj++) a[qq][jj] += qv[qq]*kv[jj];
  }
  #pragma unroll
  for (int qq=0;qq<4;qq++)
    #pragma unroll
    for (int jj=0;jj<4;jj++) e[qq][jj] = __expf(a[qq][jj]);
}

__device__ __forceinline__ void st_write(float* STb, int qi4, int ji4, const float e[4][4]){
  #pragma unroll
  for (int jj=0;jj<4;jj++)
    *(float4*)(STb + (ji4*4+jj)*64 + qi4*4) = make_float4(e[0][jj],e[1][jj],e[2][jj],e[3][jj]);
}

__device__ __forceinline__ void pv_tile(const float* STb, const float* Vb,
                                        int qp, int d4, float o[8]){
  for (int j2=0;j2<64;j2++){
    float2 sv = *(const float2*)(STb + j2*64 + qp*2);
    float4 vv4 = *(const float4*)(Vb + j2*36 + d4*4);
    float vv[4] = {vv4.x,vv4.y,vv4.z,vv4.w};
    #pragma unroll
    for (int i=0;i<4;i++){ o[i] += sv.x*vv[i]; o[4+i] += sv.y*vv[i]; }
  }
}

// ---------------- attention (both heads) + fused proj+residual+LN ----------------
template<int MODE>
__global__ __launch_bounds__(256) void k_attn_ln(const u16* __restrict__ PQK,
    const u16* __restrict__ QKWS,
    const u16* __restrict__ PV, int SV,
    const float* __restrict__ wo, const float* __restrict__ bo,
    const float* __restrict__ g, const float* __restrict__ be,
    u16* __restrict__ h, float* __restrict__ lout){
  __shared__ float sm[12672];        // 50688 B
  float* QT  = sm;                   // 4096: [h][d][q]
  float* KT  = sm + 4096;            // 2048: [d][j]
  float* VT  = sm + 6144;            // 2304: [j][36]
  float* ST  = sm + 8448;            // 4096: [j][q]; later O[tok][64]
  float* LAC = sm + 12544;           // 128
  const int t = threadIdx.x;
  const int qt = blockIdx.x, bz = blockIdx.y;
  const int j = t & 63, grp = t >> 6;
  #pragma unroll
  for (int hh=0; hh<2; hh++){
    float tmp[8];
    const u16* qrow = (MODE==0) ? (PQK + (size_t)(bz*LQ + qt*64 + j)*192)
                                : qk_rowp(PQK, QKWS, bz, qt*64 + j);
    ld8bf(qrow + hh*32 + grp*8, tmp);
    #pragma unroll
    for (int i=0;i<8;i++) QT[hh*2048 + (grp*8+i)*64 + j] = tmp[i];
  }
  if (t < 128) LAC[t] = 0.f;
  float o0[8], o1[8];
  #pragma unroll
  for (int i=0;i<8;i++){ o0[i]=0.f; o1[i]=0.f; }
  const int qi4 = t >> 4, ji4 = t & 15;
  const int qp = t >> 3, d4 = t & 7;
  float e[4][4];
  for (int kt=0; kt<32; kt++){
    #pragma unroll
    for (int hh=0; hh<2; hh++){
      __syncthreads();
      {
        float tmp[8];
        const u16* krow = (MODE==0) ? (PQK + (size_t)(bz*LQ + kt*64 + j)*192)
                                    : qk_rowp(PQK, QKWS, bz, kt*64 + j);
        ld8bf(krow + 64 + hh*32 + grp*8, tmp);
        #pragma unroll
        for (int i=0;i<8;i++) KT[(grp*8+i)*64 + j] = tmp[i];
        float tv[8];
        ld8bf(PV + (size_t)(bz*LQ + kt*64 + j)*SV + hh*32 + grp*8, tv);
        *(float4*)(VT + j*36 + grp*8)     = make_float4(tv[0],tv[1],tv[2],tv[3]);
        *(float4*)(VT + j*36 + grp*8 + 4) = make_float4(tv[4],tv[5],tv[6],tv[7]);
      }
      __syncthreads();
      score_exp_tile(QT + hh*2048, KT, qi4, ji4, e);
      st_write(ST, qi4, ji4, e);
      __syncthreads();
      if (t < 64){
        float s = 0.f;
        for (int j2=0;j2<64;j2++) s += ST[j2*64 + t];
        LAC[hh*64 + t] += s;
      }
      pv_tile(ST, VT, qp, d4, hh ? o1 : o0);
    }
  }
  __syncthreads();
  if (lout && t < 128)
    lout[(size_t)(bz*2 + (t>>6))*LQ + qt*64 + (t&63)] = LAC[t];
  {
    float i00 = 1.f/LAC[qp*2],    i01 = 1.f/LAC[qp*2+1];
    float i10 = 1.f/LAC[64+qp*2], i11 = 1.f/LAC[64+qp*2+1];
    *(float4*)(ST + (qp*2)*64 + d4*4)        = make_float4(o0[0]*i00,o0[1]*i00,o0[2]*i00,o0[3]*i00);
    *(float4*)(ST + (qp*2)*64 + 32 + d4*4)   = make_float4(o1[0]*i10,o1[1]*i10,o1[2]*i10,o1[3]*i10);
    *(float4*)(ST + (qp*2+1)*64 + d4*4)      = make_float4(o0[4]*i01,o0[5]*i01,o0[6]*i01,o0[7]*i01);
    *(float4*)(ST + (qp*2+1)*64 + 32 + d4*4) = make_float4(o1[4]*i11,o1[5]*i11,o1[6]*i11,o1[7]*i11);
  }
  for (int e2=t; e2<4096; e2+=256){ int k=e2>>6, mo=e2&63; QT[e2] = wo[mo*64+k]; }
  if (t < 64)       KT[t] = bo[t];
  else if (t < 128) KT[t] = g[t-64];
  else if (t < 192) KT[t] = be[t-128];
  __syncthreads();
  const int wid = t >> 6, lane = t & 63;
  for (int r=0; r<16; r++){
    int tl = wid*16 + r;
    size_t gtok = (size_t)(bz*LQ + qt*64 + tl);
    float acc = KT[lane];
    for (int k=0;k<64;k++) acc += ST[tl*64 + k] * QT[k*64 + lane];
    float rr = acc + bfu2f(h[gtok*64 + lane]);
    float s = rr;
    #pragma unroll
    for (int o=32;o;o>>=1) s += __shfl_xor(s,o);
    float mean = s * (1.f/64.f);
    float dv = rr - mean;
    float vs = dv*dv;
    #pragma unroll
    for (int o=32;o;o>>=1) vs += __shfl_xor(vs,o);
    float rstd = 1.f/sqrtf(vs*(1.f/64.f) + 1e-5f);
    h[gtok*64 + lane] = f2bu(dv*rstd*KT[64+lane] + KT[128+lane]);
  }
}

// ---------------- fused FFN + residual + LN ----------------
__global__ __launch_bounds__(256) void k_ffn(u16* __restrict__ h,
    const float* __restrict__ w1, const float* __restrict__ b1,
    const float* __restrict__ w2, const float* __restrict__ b2,
    const float* __restrict__ g, const float* __restrict__ be){
  __shared__ u16 W1u[64*128];
  __shared__ u16 W2u[128*64];
  __shared__ float B1[128], B2[64], G[64], Bb[64];
  const int t = threadIdx.x;
  for (int e=t; e<8192; e+=256){ int k=e>>7, mo=e&127; W1u[e] = f2bu(w1[mo*64+k]); }
  for (int e=t; e<8192; e+=256){ int k=e>>6, mo=e&63;  W2u[e] = f2bu(w2[mo*128+k]); }
  if (t < 128) B1[t] = b1[t];
  if (t < 64){ B2[t] = b2[t]; G[t] = g[t]; Bb[t] = be[t]; }
  __syncthreads();
  const int wid = t >> 6, lane = t & 63;
  const int tok0 = (blockIdx.x*4 + wid)*4;
  float x[4];
  #pragma unroll
  for (int c=0;c<4;c++) x[c] = bfu2f(h[(tok0+c)*64 + lane]);
  #pragma unroll
  for (int c=0;c<4;c++){
    float a = B1[lane], b = B1[64+lane];
    for (int k=0;k<64;k++){
      float xk = __shfl(x[c], k);
      a += xk * bfu2f(W1u[k*128 + lane]);
      b += xk * bfu2f(W1u[k*128 + 64 + lane]);
    }
    a = fmaxf(a, 0.f); b = fmaxf(b, 0.f);
    float acc = B2[lane];
    for (int k=0;k<64;k++) acc += __shfl(a,k) * bfu2f(W2u[k*64 + lane]);
    for (int k=0;k<64;k++) acc += __shfl(b,k) * bfu2f(W2u[(64+k)*64 + lane]);
    float rr = acc + x[c];
    float s = rr;
    #pragma unroll
    for (int o=32;o;o>>=1) s += __shfl_xor(s,o);
    float mean = s * (1.f/64.f);
    float dv = rr - mean;
    float vs = dv*dv;
    #pragma unroll
    for (int o=32;o;o>>=1) vs += __shfl_xor(vs,o);
    float rstd = 1.f/sqrtf(vs*(1.f/64.f) + 1e-5f);
    h[(tok0+c)*64 + lane] = f2bu(dv*rstd*G[lane] + Bb[lane]);
  }
}

// ---------------- importance: recompute scores, atomic-accumulate ----------------
__global__ __launch_bounds__(256) void k_imp(const u16* __restrict__ qk_r15,
    const u16* __restrict__ qk_ws, const float* __restrict__ l2,
    float* __restrict__ imp){
  __shared__ float sm[8320];
  float* QT   = sm;                 // 4096 [h][d][q]
  float* KT   = sm + 4096;          // 2048
  float* IMPS = sm + 6144;          // 2048
  float* INVL = sm + 8192;          // 128
  const int t = threadIdx.x;
  const int qt = blockIdx.x, bz = blockIdx.y;
  const int j = t & 63, grp = t >> 6;
  #pragma unroll
  for (int hh=0; hh<2; hh++){
    float tmp[8];
    ld8bf(qk_rowp(qk_r15, qk_ws, bz, qt*64 + j) + hh*32 + grp*8, tmp);
    #pragma unroll
    for (int i=0;i<8;i++) QT[hh*2048 + (grp*8+i)*64 + j] = tmp[i];
  }
  if (t < 128) INVL[t] = 1.f / l2[(size_t)(bz*2 + (t>>6))*LQ + qt*64 + (t&63)];
  for (int e=t; e<2048; e+=256) IMPS[e] = 0.f;
  const int qi4 = t >> 4, ji4 = t & 15;
  float e0[4][4], e1[4][4];
  for (int kt=0; kt<32; kt++){
    __syncthreads();
    {
      float tmp[8];
      ld8bf(qk_rowp(qk_r15, qk_ws, bz, kt*64 + j) + 64 + grp*8, tmp);
      #pragma unroll
      for (int i=0;i<8;i++) KT[(grp*8+i)*64 + j] = tmp[i];
    }
    __syncthreads();
    score_exp_tile(QT, KT, qi4, ji4, e0);
    __syncthreads();
    {
      float tmp[8];
      ld8bf(qk_rowp(qk_r15, qk_ws, bz, kt*64 + j) + 96 + grp*8, tmp);
      #pragma unroll
      for (int i=0;i<8;i++) KT[(grp*8+i)*64 + j] = tmp[i];
    }
    __syncthreads();
    score_exp_tile(QT + 2048, KT, qi4, ji4, e1);
    #pragma unroll
    for (int jj=0;jj<4;jj++){
      float s = 0.f;
      #pragma unroll
      for (int qq=0;qq<4;qq++)
        s += 0.5f*(e0[qq][jj]*INVL[qi4*4+qq] + e1[qq][jj]*INVL[64+qi4*4+qq]);
      atomicAdd(&IMPS[kt*64 + ji4*4 + jj], s);
    }
  }
  __syncthreads();
  for (int e=t; e<2048; e+=256) atomicAdd(&imp[bz*LQ + e], IMPS[e]);
}

// ---------------- pass2: recompute scores, write attn_w as FLOAT32 ----------------
__global__ __launch_bounds__(256) void k_pass2(const u16* __restrict__ qk_r15,
    const u16* __restrict__ qk_ws, const float* __restrict__ l2,
    float* __restrict__ wout, int bz0){
  __shared__ float sm[10624];       // 42496 B
  float* QT   = sm;                 // 4096 [h][d][q]
  float* KT   = sm + 4096;          // 2048
  float* INVL = sm + 6144;          // 128
  float* STG  = sm + 6272;          // 4352 = [64][68] f32 staging
  const int t = threadIdx.x;
  const int qt = blockIdx.x, bz = bz0 + blockIdx.y;
  const int j = t & 63, grp = t >> 6;
  #pragma unroll
  for (int hh=0; hh<2; hh++){
    float tmp[8];
    ld8bf(qk_rowp(qk_r15, qk_ws, bz, qt*64 + j) + hh*32 + grp*8, tmp);
    #pragma unroll
    for (int i=0;i<8;i++) QT[hh*2048 + (grp*8+i)*64 + j] = tmp[i];
  }
  if (t < 128) INVL[t] = 1.f / l2[(size_t)(bz*2 + (t>>6))*LQ + qt*64 + (t&63)];
  const int qi4 = t >> 4, ji4 = t & 15;
  const int wid = t >> 6;
  float e0[4][4], e1[4][4];
  for (int kt=0; kt<32; kt++){
    __syncthreads();
    {
      float tmp[8];
      ld8bf(qk_rowp(qk_r15, qk_ws, bz, kt*64 + j) + 64 + grp*8, tmp);
      #pragma unroll
      for (int i=0;i<8;i++) KT[(grp*8+i)*64 + j] = tmp[i];
    }
    __syncthreads();
    score_exp_tile(QT, KT, qi4, ji4, e0);
    __syncthreads();
    {
      float tmp[8];
      ld8bf(qk_rowp(qk_r15, qk_ws, bz, kt*64 + j) + 96 + grp*8, tmp);
      #pragma unroll
      for (int i=0;i<8;i++) KT[(grp*8+i)*64 + j] = tmp[i];
    }
    __syncthreads();
    score_exp_tile(QT + 2048, KT, qi4, ji4, e1);
    #pragma unroll
    for (int qq=0;qq<4;qq++){
      float iv0 = INVL[qi4*4+qq], iv1 = INVL[64 + qi4*4+qq];
      *(float4*)(STG + (qi4*4+qq)*68 + ji4*4) = make_float4(
        0.5f*(e0[qq][0]*iv0 + e1[qq][0]*iv1),
        0.5f*(e0[qq][1]*iv0 + e1[qq][1]*iv1),
        0.5f*(e0[qq][2]*iv0 + e1[qq][2]*iv1),
        0.5f*(e0[qq][3]*iv0 + e1[qq][3]*iv1));
    }
    __syncthreads();
    {
      size_t base = 1 + (size_t)bz*LQ*LQ + (size_t)(qt*64)*LQ + (size_t)kt*64;
      for (int r=0;r<16;r++){
        int q = wid*16 + r;
        wout[base + (size_t)q*LQ + j] = STG[q*68 + j];
      }
    }
  }
}

// ---------------- top-k (M=8, ties -> lowest index) — LDS serial ----------------
__global__ __launch_bounds__(64) void k_topk(const float* __restrict__ imp,
                                             int* __restrict__ topki){
  __shared__ float v[2048];
  __shared__ float bv[64];
  __shared__ int   bi[64];
  __shared__ int   chosen;
  const int b = blockIdx.x, lane = threadIdx.x;
  for (int i=lane; i<2048; i+=64) v[i] = imp[b*2048 + i];
  __syncthreads();
  for (int m=0; m<8; m++){
    float best = -1e30f; int besti = 1<<30;
    for (int i=lane; i<2048; i+=64)
      if (v[i] > best || (v[i] == best && i < besti)){ best = v[i]; besti = i; }
    bv[lane] = best; bi[lane] = besti;
    __syncthreads();
    if (lane == 0){
      float B = bv[0]; int I = bi[0];
      for (int i2=1; i2<64; i2++)
        if (bv[i2] > B || (bv[i2] == B && bi[i2] < I)){ B = bv[i2]; I = bi[i2]; }
      topki[b*8 + m] = (I < 0) ? 0 : (I > 2047 ? 2047 : I);
      chosen = (I < 0) ? 0 : (I > 2047 ? 2047 : I);
    }
    __syncthreads();
    if (lane == 0) v[chosen] = -1e30f;
    __syncthreads();
  }
}

// ---------------- memory reader + loss — LDS serial; f32 loss to d_ws ----------------
__global__ __launch_bounds__(64) void k_loss(const u16* __restrict__ h,
    const int* __restrict__ topki, const int* __restrict__ query, const int* __restrict__ target,
    const float* __restrict__ qemb, const float* __restrict__ rq_w, const float* __restrict__ rq_b,
    const float* __restrict__ ro_w, const float* __restrict__ ro_b, float* __restrict__ loss_out){
  __shared__ float mvs[8][64];
  __shared__ float qhs[64], col[64], rds[64], lgs[64];
  __shared__ float scs[8];
  __shared__ float lossacc;
  const int lane = threadIdx.x;
  if (lane == 0) lossacc = 0.f;
  for (int b=0; b<BBATCH; b++){
    __syncthreads();
    #pragma unroll
    for (int m=0; m<8; m++){
      int idx = topki[b*8+m] & 2047;
      mvs[m][lane] = bfu2f(h[(size_t)(b*LQ + idx)*64 + lane]);
    }
    qhs[lane] = qemb[((query[b]&63)<<6) + lane];
    __syncthreads();
    float qd = rq_b[lane];
    for (int k=0;k<64;k++) qd += qhs[k] * rq_w[lane*64 + k];
    for (int m=0; m<8; m++){
      col[lane] = qd * mvs[m][lane];
      __syncthreads();
      if (lane == 0){
        float s = 0.f;
        for (int i2=0;i2<64;i2++) s += col[i2];
        scs[m] = s * 0.125f;   // 1/sqrt(64)
      }
      __syncthreads();
    }
    float mx = scs[0];
    #pragma unroll
    for (int m=1;m<8;m++) mx = fmaxf(mx, scs[m]);
    float wm[8]; float den = 0.f;
    #pragma unroll
    for (int m=0;m<8;m++){ wm[m] = __expf(scs[m]-mx); den += wm[m]; }
    float rd = 0.f;
    #pragma unroll
    for (int m=0;m<8;m++) rd += (wm[m]/den) * mvs[m][lane];
    rds[lane] = rd;
    __syncthreads();
    float lg = ro_b[lane];
    for (int d=0;d<64;d++) lg += rds[d] * ro_w[lane*64 + d];
    lgs[lane] = lg;
    __syncthreads();
    if (lane == 0){
      float lmx = lgs[0];
      for (int i2=1;i2<64;i2++) lmx = fmaxf(lmx, lgs[i2]);
      float es = 0.f;
      for (int i2=0;i2<64;i2++) es += __expf(lgs[i2]-lmx);
      float lt = lgs[target[b]&63];
      lossacc -= (lt - lmx - logf(es));
    }
  }
  __syncthreads();
  if (lane == 0) loss_out[0] = lossacc * (1.f/16.f);
}

// ---------------- final: f32 loss -> out_f[0] (runs LAST) ----------------
__global__ void k_store_loss(const float* __restrict__ ls, float* __restrict__ out){
  out[0] = ls[0];
}

// ---------------- launch ----------------
extern "C" void kernel_launch(void* const* d_in, const int* in_sizes, int n_in,
                              void* d_out, int out_size, void* d_ws, size_t ws_size,
                              hipStream_t stream){
  const int*   seq    = (const int*)  d_in[0];
  const int*   query  = (const int*)  d_in[1];
  const int*   target = (const int*)  d_in[2];
  const float* embed  = (const float*)d_in[3];
  const float* a1_wi  = (const float*)d_in[4];
  const float* a1_bi  = (const float*)d_in[5];
  const float* a1_wo  = (const float*)d_in[6];
  const float* a1_bo  = (const float*)d_in[7];
  const float* ff1_w1 = (const float*)d_in[8];
  const float* ff1_b1 = (const float*)d_in[9];
  const float* ff1_w2 = (const float*)d_in[10];
  const float* ff1_b2 = (const float*)d_in[11];
  const float* ln1a_g = (const float*)d_in[12];
  const float* ln1a_b = (const float*)d_in[13];
  const float* ln1b_g = (const float*)d_in[14];
  const float* ln1b_b = (const float*)d_in[15];
  const float* a2_wi  = (const float*)d_in[16];
  const float* a2_bi  = (const float*)d_in[17];
  const float* a2_wo  = (const float*)d_in[18];
  const float* a2_bo  = (const float*)d_in[19];
  const float* ff2_w1 = (const float*)d_in[20];
  const float* ff2_b1 = (const float*)d_in[21];
  const float* ff2_w2 = (const float*)d_in[22];
  const float* ff2_b2 = (const float*)d_in[23];
  const float* ln2a_g = (const float*)d_in[24];
  const float* ln2a_b = (const float*)d_in[25];
  const float* ln2b_g = (const float*)d_in[26];
  const float* ln2b_b = (const float*)d_in[27];
  const float* rq_w   = (const float*)d_in[28];
  const float* rq_b   = (const float*)d_in[29];
  const float* ro_w   = (const float*)d_in[30];
  const float* ro_b   = (const float*)d_in[31];
  const float* qemb   = (const float*)d_in[32];

  // d_ws (918,020 B)
  char* wsb      = (char*)d_ws;
  u16*  qk_ws    = (u16*)(wsb);                // 524,288 B (batch 15 [Qs|K])
  float* ws_imp  = (float*)(wsb + 524288);     // 131,072 B
  float* ws_l    = (float*)(wsb + 655360);     // 262,144 B
  int*  ws_top   = (int*)(wsb + 917504);       // 512 B
  float* ws_loss = (float*)(wsb + 918016);     // 4 B

  // d_out (FLOAT32, 268,435,460 B) + scratch parking
  float* out_f  = (float*)d_out;
  u16* h16     = (u16*)((char*)d_out + 64);          // 4 MB bf16, region 0
  u16* do_qkv  = (u16*)((char*)d_out + 4194368);     // 12 MB bf16 (then V 4 MB)
  u16* do_v    = do_qkv;
  u16* qk_r15  = (u16*)((char*)d_out + 251658304);   // 7.7 MB, region 15

  k_embed<<<8192,256,0,stream>>>(seq, embed, h16);
  k_zero<<<128,256,0,stream>>>(ws_imp);
  // layer 1
  k_qkv<0><<<2048,256,0,stream>>>(h16, a1_wi, a1_bi, do_qkv, nullptr, nullptr, nullptr);
  k_attn_ln<0><<<dim3(32,16),256,0,stream>>>(do_qkv, nullptr, do_qkv+128, 192,
                                             a1_wo, a1_bo, ln1a_g, ln1a_b, h16, nullptr);
  k_ffn<<<2048,256,0,stream>>>(h16, ff1_w1, ff1_b1, ff1_w2, ff1_b2, ln1b_g, ln1b_b);
  // layer 2
  k_qkv<1><<<2048,256,0,stream>>>(h16, a2_wi, a2_bi, nullptr, qk_r15, qk_ws, do_v);
  k_attn_ln<1><<<dim3(32,16),256,0,stream>>>(qk_r15, qk_ws, do_v, 64,
                                             a2_wo, a2_bo, ln2a_g, ln2a_b, h16, ws_l);
  k_ffn<<<2048,256,0,stream>>>(h16, ff2_w1, ff2_b1, ff2_w2, ff2_b2, ln2b_g, ln2b_b);
  // importance -> topk -> loss (loss to d_ws; h16 still alive)
  k_imp<<<dim3(32,16),256,0,stream>>>(qk_r15, qk_ws, ws_l, ws_imp);
  k_topk<<<16,64,0,stream>>>(ws_imp, ws_top);
  k_loss<<<1,64,0,stream>>>(h16, ws_top, query, target, qemb, rq_w, rq_b, ro_w, ro_b, ws_loss);
  // attn_w FLOAT32 (destroys d_out scratch): wave1 b0-14, wave2 b15
  k_pass2<<<dim3(32,15),256,0,stream>>>(qk_r15, qk_ws, ws_l, out_f, 0);
  k_pass2<<<dim3(32,1),256,0,stream>>>(qk_r15, qk_ws, ws_l, out_f, 15);
  // loss stored LAST
  k_store_loss<<<1,1,0,stream>>>(ws_loss, out_f);
}